// Round 18
// baseline (121.212 us; speedup 1.0000x reference)
//
#include <hip/hip_runtime.h>
#include <hip/hip_bf16.h>

#define NN 1024
#define LOG2E 1.44269504088896f

typedef __attribute__((ext_vector_type(8))) short short8;
typedef __attribute__((ext_vector_type(4))) float floatx4;
typedef __attribute__((ext_vector_type(4))) int intx4;
typedef __attribute__((ext_vector_type(2))) int intx2;

#define WAIT_VM0()   asm volatile("s_waitcnt vmcnt(0)" ::: "memory")
#define WAIT_VM8()   asm volatile("s_waitcnt vmcnt(8)" ::: "memory")
#define WAIT_LGKM0() asm volatile("s_waitcnt lgkmcnt(0)" ::: "memory")

// fast f32->bf16 (round-half-up) pack of two floats into one dword
static __device__ __forceinline__ unsigned pk2(float f0, float f1) {
    unsigned u0 = __float_as_uint(f0) + 0x8000u;
    unsigned u1 = __float_as_uint(f1) + 0x8000u;
    return __builtin_amdgcn_perm(u1, u0, 0x07060302u);   // [u1.hi16 : u0.hi16]
}
static __device__ __forceinline__ short8 pk8(floatx4 v0, floatx4 v1) {
    union { intx4 i; short8 s; } u;
    u.i[0] = (int)pk2(v0[0], v0[1]); u.i[1] = (int)pk2(v0[2], v0[3]);
    u.i[2] = (int)pk2(v1[0], v1[1]); u.i[3] = (int)pk2(v1[2], v1[3]);
    return u.s;
}
// async global->LDS, 16B/lane, dest = ldsbase + lane*16
static __device__ __forceinline__ void load_lds16(const void* gsrc, void* lds) {
    __builtin_amdgcn_global_load_lds(
        (const __attribute__((address_space(1))) void*)gsrc,
        (__attribute__((address_space(3))) void*)lds, 16, 0, 0);
}

// ================= K0: prep — WTb transpose, pwb cast, adj bitmask =================
__global__ __launch_bounds__(256) void prep_kernel(
    const float* __restrict__ W, const float* __restrict__ proj_w,
    const int* __restrict__ adj,
    __hip_bfloat16* __restrict__ WTb,    // [256 o][256 k], o = hh*64+d
    __hip_bfloat16* __restrict__ pwb,    // [256 o][256 k]
    unsigned* __restrict__ adjm)         // [1024][32]
{
    int blk = blockIdx.x, t = threadIdx.x;
    if (blk < 16) {
        int o = blk * 16 + (t >> 4);
        int hh = o >> 6, d = o & 63;
        #pragma unroll
        for (int kk = 0; kk < 16; ++kk) {
            int k = (t & 15) + 16 * kk;
            WTb[(size_t)o * 256 + k] = __float2bfloat16(W[((size_t)hh * 256 + k) * 64 + d]);
        }
    } else if (blk < 32) {
        size_t base = (size_t)(blk - 16) * 4096 + (size_t)t * 16;
        #pragma unroll
        for (int k = 0; k < 16; k += 8) {
            floatx4 v0 = *(const floatx4*)(proj_w + base + k);
            floatx4 v1 = *(const floatx4*)(proj_w + base + k + 4);
            *(short8*)(pwb + base + k) = pk8(v0, v1);
        }
    } else {
        int n = (blk - 32) * 8 + (t >> 5);
        int wd = t & 31;
        const int* arow = adj + (size_t)n * NN + wd * 32;
        unsigned bits = 0;
        #pragma unroll
        for (int j4 = 0; j4 < 8; ++j4) {
            intx4 v = *(const intx4*)(arow + j4 * 4);
            #pragma unroll
            for (int j = 0; j < 4; ++j) if (v[j] != 0) bits |= (1u << (j4 * 4 + j));
        }
        adjm[(size_t)n * 32 + wd] = bits;
    }
}

// ================= K1: Wh GEMM — async single-buffer staging + explicit fences =================
// grid = 512 x 256t (4 waves). Wave w = d-slice w; tile j = head j (ct = w + 4j).
__global__ __launch_bounds__(256) void wh_kernel(
    const float* __restrict__ h,
    const __hip_bfloat16* __restrict__ WTb,
    const float* __restrict__ a1, const float* __restrict__ a2,
    __hip_bfloat16* __restrict__ WhT,   // [B*H][64][NN]
    float* __restrict__ si, float* __restrict__ sj)   // PRESCALED by log2e
{
    int t = threadIdx.x;
    int w = t >> 6, l = t & 63;
    int rl = l & 15, q = l >> 4;
    int r0 = blockIdx.x * 16;
    int bb = r0 >> 10, n0 = r0 & 1023;

    __shared__ __align__(16) __hip_bfloat16 bst[4][4096];
    __shared__ float redsi[4][4][16];
    __shared__ float redsj[4][4][16];

    // A-frags from h (f32 -> bf16 pack)
    short8 af[8];
    const float* Arow = h + (size_t)(r0 + rl) * 256 + q * 8;
    #pragma unroll
    for (int k0 = 0; k0 < 8; ++k0) {
        floatx4 v0 = *(const floatx4*)(Arow + k0 * 32);
        floatx4 v1 = *(const floatx4*)(Arow + k0 * 32 + 4);
        af[k0] = pk8(v0, v1);
    }

    // stage tile j=0 (ct = w): inst k covers rows k*2+(l>>5); swizzle g = (l&31) ^ (row&7)
    #pragma unroll
    for (int k = 0; k < 8; ++k) {
        int row = k * 2 + (l >> 5);
        int g = (l & 31) ^ (row & 7);
        load_lds16(WTb + (size_t)w * 4096 + row * 256 + g * 8, &bst[w][k * 512]);
    }

    #pragma unroll
    for (int j = 0; j < 4; ++j) {       // ct = w + 4j -> head j, d-slice w
        WAIT_VM0();                      // tile-j DMAs landed in LDS
        floatx4 acc = {0.f, 0.f, 0.f, 0.f};
        #pragma unroll
        for (int k0 = 0; k0 < 8; ++k0) {
            int p = ((k0 << 2) + q) ^ (rl & 7);
            short8 bf = *(const short8*)(&bst[w][rl * 256 + p * 8]);
            acc = __builtin_amdgcn_mfma_f32_16x16x32_bf16(af[k0], bf, acc, 0, 0, 0);
        }
        WAIT_LGKM0();                    // ds_reads retired to VGPRs; LDS may be overwritten
        if (j < 3) {                     // issue loads(j+1); epilogue below is the blanket
            int ctn = w + 4 * (j + 1);
            #pragma unroll
            for (int k = 0; k < 8; ++k) {
                int row = k * 2 + (l >> 5);
                int g = (l & 31) ^ (row & 7);
                load_lds16(WTb + (size_t)ctn * 4096 + row * 256 + g * 8, &bst[w][k * 512]);
            }
        }

        // WhT[bh = bb*4+j][d = w*16+rl][n = n0+q*4 ..]
        intx2 pr;
        pr[0] = (int)pk2(acc[0], acc[1]);
        pr[1] = (int)pk2(acc[2], acc[3]);
        *(intx2*)(WhT + ((size_t)(bb * 4 + j) * 64 + w * 16 + rl) * NN + n0 + q * 4) = pr;

        // si/sj partials (prescaled by log2e), reduce over this wave's 16 d's
        float av1 = a1[j * 64 + w * 16 + rl] * LOG2E;
        float av2 = a2[j * 64 + w * 16 + rl] * LOG2E;
        #pragma unroll
        for (int i = 0; i < 4; ++i) {
            float p1 = acc[i] * av1, p2 = acc[i] * av2;
            #pragma unroll
            for (int off = 1; off < 16; off <<= 1) {
                p1 += __shfl_xor(p1, off, 64);
                p2 += __shfl_xor(p2, off, 64);
            }
            if (rl == 0) { redsi[w][j][q * 4 + i] = p1; redsj[w][j][q * 4 + i] = p2; }
        }
    }
    __syncthreads();

    if (t < 64) {
        int head = t >> 4, row = t & 15;
        si[(size_t)(bb * 4 + head) * NN + n0 + row] =
            redsi[0][head][row] + redsi[1][head][row] + redsi[2][head][row] + redsi[3][head][row];
    } else if (t < 128) {
        int u = t - 64;
        int head = u >> 4, row = u & 15;
        sj[(size_t)(bb * 4 + head) * NN + n0 + row] =
            redsj[0][head][row] + redsj[1][head][row] + redsj[2][head][row] + redsj[3][head][row];
    }
}

// ================= K2: attn (async DOUBLE-buffer, never-drain vmcnt(8)) + proj + LN fused =================
// grid = 512 x 256t. Block = (b, 16-token tile); wave w = head w in attn phase.
// LDS (75520 B): bst 4x2x8192B @0 | pl 4x16x72 @65536 | rinvs @74752 | red @75008
// proj overlay: pbst = wave's own bst[w] buf0 (4096 elems) | hm 16x264 @65536
__global__ __launch_bounds__(256) void attn_proj_kernel(
    const unsigned* __restrict__ adjm,
    const __hip_bfloat16* __restrict__ WhT,
    const float* __restrict__ si, const float* __restrict__ sj,
    const __hip_bfloat16* __restrict__ pwb,
    const float* __restrict__ h,
    const float* __restrict__ proj_b, const float* __restrict__ gamma,
    const float* __restrict__ beta,
    float* __restrict__ out)
{
    __shared__ __align__(16) char smem[75520];
    auto bst   = reinterpret_cast<__hip_bfloat16 (*)[2][4096]>(smem);         // [4][2][4096]
    auto pl    = reinterpret_cast<__hip_bfloat16 (*)[16][72]>(smem + 65536);
    auto rinvs = reinterpret_cast<float (*)[16]>(smem + 74752);
    auto hm    = reinterpret_cast<__hip_bfloat16 (*)[264]>(smem + 65536);     // proj overlay
    auto red   = reinterpret_cast<float (*)[4][16]>(smem + 75008);

    int bx = blockIdx.x, t = threadIdx.x;
    int w = t >> 6, l = t & 63;
    int rl = l & 15, q = l >> 4;
    int b = bx >> 6, n0 = (bx & 63) * 16;
    int bh = b * 4 + w;
    int r0 = bx * 16;

    int r = l >> 2, cg = l & 3;          // score roles: row r, 16-entry chunk cg
    float sii = si[(size_t)bh * NN + n0 + r];
    const float* sjr = sj + (size_t)bh * NN;
    const unsigned* amrow = adjm + (size_t)(n0 + r) * 32;

    float lsum = 0.f;
    floatx4 acc[4] = { {0,0,0,0}, {0,0,0,0}, {0,0,0,0}, {0,0,0,0} };

    const __hip_bfloat16* Bhead = WhT + (size_t)bh * 64 * NN;
    int lrow = l >> 3;                   // 0..7
    int lgrp = (l & 7) ^ lrow;           // XOR swizzle group (row&7 == lrow)

    // prologue: issue tile 0 into buf0
    #pragma unroll
    for (int k = 0; k < 8; ++k)
        load_lds16(Bhead + (size_t)(k * 8 + lrow) * NN + lgrp * 8, &bst[w][0][k * 512]);

#define SCORES(IT)                                                              \
    do {                                                                        \
        int m0_ = (IT) * 64;                                                    \
        int mb_ = m0_ + cg * 16;                                                \
        unsigned bits_ = amrow[(m0_ >> 5) + (cg >> 1)] >> ((cg & 1) * 16);      \
        _Pragma("unroll")                                                       \
        for (int c4 = 0; c4 < 4; ++c4) {                                        \
            floatx4 s4_ = *(const floatx4*)(sjr + mb_ + c4 * 4);                \
            float pv_[4];                                                       \
            _Pragma("unroll")                                                   \
            for (int k = 0; k < 4; ++k) {                                       \
                float x_ = sii + s4_[k];                                        \
                x_ = fmaxf(x_, 0.2f * x_);                                      \
                x_ = ((bits_ >> (c4 * 4 + k)) & 1u) ? x_ : -1e9f;               \
                pv_[k] = exp2f(x_);                                             \
                lsum += pv_[k];                                                 \
            }                                                                   \
            intx2 two_;                                                         \
            two_[0] = (int)pk2(pv_[0], pv_[1]);                                 \
            two_[1] = (int)pk2(pv_[2], pv_[3]);                                 \
            *(intx2*)(&pl[w][r][cg * 16 + c4 * 4]) = two_;                      \
        }                                                                       \
    } while (0)

#define MFMA_TILE(CUR)                                                          \
    do {                                                                        \
        _Pragma("unroll")                                                       \
        for (int ks = 0; ks < 2; ++ks) {                                        \
            short8 afr_ = *(const short8*)(&pl[w][rl][ks * 32 + q * 8]);        \
            _Pragma("unroll")                                                   \
            for (int dt = 0; dt < 4; ++dt) {                                    \
                int p_ = ((ks << 2) + q) ^ (rl & 7);                            \
                short8 bfr_ = *(const short8*)(&bst[w][CUR][(dt * 16 + rl) * 64 + p_ * 8]); \
                acc[dt] = __builtin_amdgcn_mfma_f32_16x16x32_bf16(afr_, bfr_, acc[dt], 0, 0, 0); \
            }                                                                   \
        }                                                                       \
    } while (0)

    for (int it = 0; it < 15; ++it) {
        int cur = it & 1;
        // issue tile it+1 into the other buffer (stays in flight across MFMA(it))
        int m1 = (it + 1) * 64;
        #pragma unroll
        for (int k = 0; k < 8; ++k)
            load_lds16(Bhead + (size_t)(k * 8 + lrow) * NN + m1 + lgrp * 8,
                       &bst[w][cur ^ 1][k * 512]);
        SCORES(it);          // VALU blanket; its own loads drain only OLDER vmem ops
        WAIT_VM8();          // tile-it (oldest 8+) landed; tile-it+1 may remain in flight
        MFMA_TILE(cur);      // buf cur; ds_reads retire before next iteration's DMA issue
    }
    // peeled last iteration: nothing newer in flight -> full drain required
    SCORES(15);
    WAIT_VM0();
    MFMA_TILE(1);            // 15 & 1

#undef SCORES
#undef MFMA_TILE

    // softmax denominators: reduce over 4 lanes sharing row r (same-wave)
    lsum += __shfl_xor(lsum, 1, 64);
    lsum += __shfl_xor(lsum, 2, 64);
    if (cg == 0) rinvs[w][r] = 1.f / lsum;
    float riv[4];
    #pragma unroll
    for (int i = 0; i < 4; ++i) riv[i] = rinvs[w][q * 4 + i];

    // proj B tile j=0 into this wave's own (dead) buf0 — in flight across the barriers
    __hip_bfloat16* pb = &bst[w][0][0];
    #pragma unroll
    for (int k = 0; k < 8; ++k) {
        int row = k * 2 + (l >> 5);
        int g = (l & 31) ^ (row & 7);
        load_lds16(pwb + (size_t)w * 4096 + row * 256 + g * 8, pb + k * 512);
    }

    __syncthreads();    // all waves done with pl reads; hm may overwrite pl region
    #pragma unroll
    for (int dt = 0; dt < 4; ++dt) {
        #pragma unroll
        for (int i = 0; i < 4; ++i) {
            unsigned uv = (__float_as_uint(acc[dt][i] * riv[i]) + 0x8000u) >> 16;
            hm[q * 4 + i][w * 64 + dt * 16 + rl] = __ushort_as_bfloat16((unsigned short)uv);
        }
    }
    __syncthreads();    // hm complete (all heads)

    // ---- proj: A from hm, B async-staged via wave-private pb; wave w tiles ct = w + 4j ----
    short8 paf[8];
    #pragma unroll
    for (int k0 = 0; k0 < 8; ++k0) paf[k0] = *(const short8*)(&hm[rl][q * 8 + k0 * 32]);

    floatx4 pacc[4];
    #pragma unroll
    for (int j = 0; j < 4; ++j) {
        WAIT_VM0();                      // tile-j DMAs landed
        floatx4 a = {0.f, 0.f, 0.f, 0.f};
        #pragma unroll
        for (int k0 = 0; k0 < 8; ++k0) {
            int p = ((k0 << 2) + q) ^ (rl & 7);
            short8 bf = *(const short8*)(pb + rl * 256 + p * 8);
            a = __builtin_amdgcn_mfma_f32_16x16x32_bf16(paf[k0], bf, a, 0, 0, 0);
        }
        pacc[j] = a;
        WAIT_LGKM0();                    // ds_reads retired; safe to overwrite
        if (j < 3) {
            int ctn = w + 4 * (j + 1);
            #pragma unroll
            for (int k = 0; k < 8; ++k) {
                int row = k * 2 + (l >> 5);
                int g = (l & 31) ^ (row & 7);
                load_lds16(pwb + (size_t)ctn * 4096 + row * 256 + g * 8, pb + k * 512);
            }
        }
    }

    // bias + residual + LayerNorm
    float ps[4] = {0.f, 0.f, 0.f, 0.f};
    #pragma unroll
    for (int j = 0; j < 4; ++j) {
        int col = (w + j * 4) * 16 + rl;
        float pbias = proj_b[col];
        #pragma unroll
        for (int i = 0; i < 4; ++i) {
            float v = pacc[j][i] + pbias + h[(size_t)(r0 + q * 4 + i) * 256 + col];
            pacc[j][i] = v;
            ps[i] += v;
        }
    }
    #pragma unroll
    for (int i = 0; i < 4; ++i) {
        float s = ps[i];
        #pragma unroll
        for (int off = 1; off < 16; off <<= 1) s += __shfl_xor(s, off, 64);
        ps[i] = s;
    }
    if (rl == 0) {
        for (int i = 0; i < 4; ++i) red[0][w][q * 4 + i] = ps[i];
    }
    __syncthreads();
    float mu[4];
    #pragma unroll
    for (int i = 0; i < 4; ++i) {
        int row = q * 4 + i;
        mu[i] = (red[0][0][row] + red[0][1][row] + red[0][2][row] + red[0][3][row]) * (1.f / 256.f);
    }
    float vs[4] = {0.f, 0.f, 0.f, 0.f};
    #pragma unroll
    for (int j = 0; j < 4; ++j) {
        #pragma unroll
        for (int i = 0; i < 4; ++i) { float cv = pacc[j][i] - mu[i]; vs[i] += cv * cv; }
    }
    #pragma unroll
    for (int i = 0; i < 4; ++i) {
        float s = vs[i];
        #pragma unroll
        for (int off = 1; off < 16; off <<= 1) s += __shfl_xor(s, off, 64);
        vs[i] = s;
    }
    if (rl == 0) {
        for (int i = 0; i < 4; ++i) red[1][w][q * 4 + i] = vs[i];
    }
    __syncthreads();
    float rs[4];
    #pragma unroll
    for (int i = 0; i < 4; ++i) {
        int row = q * 4 + i;
        float var = (red[1][0][row] + red[1][1][row] + red[1][2][row] + red[1][3][row]) * (1.f / 256.f);
        rs[i] = rsqrtf(var + 1e-5f);
    }
    #pragma unroll
    for (int j = 0; j < 4; ++j) {
        int col = (w + j * 4) * 16 + rl;
        float g = gamma[col], be = beta[col];
        #pragma unroll
        for (int i = 0; i < 4; ++i)
            out[(size_t)(r0 + q * 4 + i) * 256 + col] = (pacc[j][i] - mu[i]) * rs[i] * g + be;
    }
}

extern "C" void kernel_launch(void* const* d_in, const int* in_sizes, int n_in,
                              void* d_out, int out_size, void* d_ws, size_t ws_size,
                              hipStream_t stream) {
    const float* h      = (const float*)d_in[0];
    const int*   adj    = (const int*)d_in[1];
    const float* W      = (const float*)d_in[2];
    const float* a1     = (const float*)d_in[3];
    const float* a2     = (const float*)d_in[4];
    const float* proj_w = (const float*)d_in[5];
    const float* proj_b = (const float*)d_in[6];
    const float* gamma  = (const float*)d_in[7];
    const float* beta   = (const float*)d_in[8];
    float* out = (float*)d_out;

    char* ws = (char*)d_ws;
    __hip_bfloat16* WhT = (__hip_bfloat16*)ws;   ws += (size_t)32 * 64 * NN * 2;   // 4 MB
    __hip_bfloat16* WTb = (__hip_bfloat16*)ws;   ws += 256 * 256 * 2;              // 128 KB
    __hip_bfloat16* pwb = (__hip_bfloat16*)ws;   ws += 256 * 256 * 2;              // 128 KB
    float* si = (float*)ws;                      ws += (size_t)32 * NN * 4;        // 128 KB
    float* sj = (float*)ws;                      ws += (size_t)32 * NN * 4;        // 128 KB
    unsigned* adjm = (unsigned*)ws;              ws += (size_t)NN * 32 * 4;        // 128 KB

    prep_kernel<<<160, 256, 0, stream>>>(W, proj_w, adj, WTb, pwb, adjm);
    wh_kernel<<<512, 256, 0, stream>>>(h, WTb, a1, a2, WhT, si, sj);
    attn_proj_kernel<<<512, 256, 0, stream>>>(adjm, WhT, si, sj, pwb, h, proj_b, gamma, beta, out);
}